// Round 9
// baseline (138.091 us; speedup 1.0000x reference)
//
#include <hip/hip_runtime.h>
#include <hip/hip_bf16.h>
#include <limits.h>

#define NUM_NODES 100000
#define OUT_CH 64
#define NUM_EDGES 3200000
#define BROWS 128                    // rows per bucket
#define NBUCK 782                    // ceil(100000/128); 782*128 = 100096
#define NPBLK 256                    // partition blocks
#define EPB (NUM_EDGES / NPBLK)      // 12500 edges per partition block
#define I4PB (EPB / 4)               // 3125 int4 per partition block
#define STAGECAP 6144                // per-bucket LDS sort cap (avg 4092, max ~4500)
#define NTRANS 1563                  // transpose blocks: ceil(100000/64)

// ---------- K1: fused [transpose W -> bf16 Wtb] + [two-stage min] ----------
__global__ __launch_bounds__(256) void LINK_62689342652831_mintrans_kernel(
    const float* __restrict__ W, unsigned short* __restrict__ Wtb,
    const int* __restrict__ rows, int* __restrict__ minp) {
    __shared__ float tile[64][65];
    if (blockIdx.x < NTRANS) {
        int n0 = blockIdx.x * 64;
        int tx = threadIdx.x & 63;
        int ty = threadIdx.x >> 6;
        for (int c = ty; c < 64; c += 4) {
            int n = n0 + tx;
            tile[c][tx] = (n < NUM_NODES) ? W[(size_t)c * NUM_NODES + n] : 0.0f;
        }
        __syncthreads();
        for (int i = ty; i < 64; i += 4) {
            int n = n0 + i;
            if (n < NUM_NODES) {
                __hip_bfloat16 bv = __float2bfloat16(tile[tx][i]);
                Wtb[(size_t)n * OUT_CH + tx] = *(unsigned short*)&bv;
            }
        }
    } else {
        int blk = blockIdx.x - NTRANS;  // 0..255
        int tid = blk * 256 + threadIdx.x;
        int stride = 256 * 256;
        const int4* r4 = (const int4*)rows;
        int m = INT_MAX;
        for (int i = tid; i < NUM_EDGES / 4; i += stride) {
            int4 v = r4[i];
            m = min(m, min(min(v.x, v.y), min(v.z, v.w)));
        }
        for (int off = 32; off > 0; off >>= 1) m = min(m, __shfl_xor(m, off, 64));
        int* sm = (int*)tile;
        if ((threadIdx.x & 63) == 0) sm[threadIdx.x >> 6] = m;
        __syncthreads();
        if (threadIdx.x == 0) {
            int mm = min(min(sm[0], sm[1]), min(sm[2], sm[3]));
            atomicMin(minp, mm);
        }
    }
}

// ---------- K3: per-block bucket histogram -> hist2d[blk][bucket] ----------
__global__ __launch_bounds__(512) void LINK_62689342652831_hist2d_kernel(
    const int* __restrict__ rows, const int* __restrict__ minp,
    int* __restrict__ hist2d) {
    __shared__ int h[NBUCK];
    for (int i = threadIdx.x; i < NBUCK; i += 512) h[i] = 0;
    __syncthreads();
    int minv = *minp;
    int blk = blockIdx.x;
    const int4* r4 = (const int4*)rows;
    for (int i = threadIdx.x; i < I4PB; i += 512) {
        int4 v = r4[blk * I4PB + i];
        atomicAdd(&h[(unsigned)(v.x - minv) >> 7], 1);
        atomicAdd(&h[(unsigned)(v.y - minv) >> 7], 1);
        atomicAdd(&h[(unsigned)(v.z - minv) >> 7], 1);
        atomicAdd(&h[(unsigned)(v.w - minv) >> 7], 1);
    }
    __syncthreads();
    for (int i = threadIdx.x; i < NBUCK; i += 512) hist2d[blk * NBUCK + i] = h[i];
}

// ---------- K4a: per-bucket prefix over the 256 blocks (in-place) ----------
__global__ __launch_bounds__(512) void LINK_62689342652831_colscan_kernel(
    int* __restrict__ hist2d, int* __restrict__ totals) {
    int lane = threadIdx.x & 63;
    int wid = threadIdx.x >> 6;
    int b = blockIdx.x * 8 + wid;
    if (b >= NBUCK) return;
    int carry = 0;
    for (int rnd = 0; rnd < NPBLK / 64; ++rnd) {
        int blk = rnd * 64 + lane;
        int v = hist2d[blk * NBUCK + b];
        int x = v;
        for (int off = 1; off < 64; off <<= 1) {
            int y = __shfl_up(x, off, 64);
            if (lane >= off) x += y;
        }
        hist2d[blk * NBUCK + b] = x - v + carry;  // exclusive + carry
        carry += __shfl(x, 63, 64);
    }
    if (lane == 0) totals[b] = carry;
}

// ---------- K4b: scan bucket totals -> bstart[0..NBUCK] ----------
__global__ __launch_bounds__(1024) void LINK_62689342652831_bscan_kernel(
    const int* __restrict__ totals, int* __restrict__ bstart) {
    __shared__ int ss[1024];
    int t = threadIdx.x;
    int v = (t < NBUCK) ? totals[t] : 0;
    ss[t] = v;
    __syncthreads();
    for (int off = 1; off < 1024; off <<= 1) {
        int x = (t >= off) ? ss[t - off] : 0;
        __syncthreads();
        ss[t] += x;
        __syncthreads();
    }
    if (t < NBUCK) bstart[t] = ss[t] - v;
    if (t == NBUCK - 1) bstart[NBUCK] = ss[t];
}

// ---------- K5: partition edges into bucket regions (no global atomics) ----------
__global__ __launch_bounds__(512) void LINK_62689342652831_part_kernel(
    const int* __restrict__ rows, const int* __restrict__ cols,
    const int* __restrict__ minp, const int* __restrict__ hist2d,
    const int* __restrict__ bstart, unsigned int* __restrict__ packed) {
    __shared__ int offs_l[NBUCK];
    __shared__ int lcur[NBUCK];
    int blk = blockIdx.x;
    for (int i = threadIdx.x; i < NBUCK; i += 512) {
        offs_l[i] = bstart[i] + hist2d[blk * NBUCK + i];
        lcur[i] = 0;
    }
    __syncthreads();
    int minv = *minp;
    const int4* r4 = (const int4*)rows;
    const int4* c4 = (const int4*)cols;
    for (int i = threadIdx.x; i < I4PB; i += 512) {
        int4 rv = r4[blk * I4PB + i];
        int4 cv = c4[blk * I4PB + i];
#pragma unroll
        for (int k = 0; k < 4; ++k) {
            int r = ((k == 0) ? rv.x : (k == 1) ? rv.y : (k == 2) ? rv.z : rv.w) - minv;
            int c = (k == 0) ? cv.x : (k == 1) ? cv.y : (k == 2) ? cv.z : cv.w;
            int b = (unsigned)r >> 7;
            int pos = offs_l[b] + atomicAdd(&lcur[b], 1);
            packed[pos] = ((unsigned)(r & (BROWS - 1)) << 17) | (unsigned)c;
        }
    }
}

// ---------- K6: reg-staged counting-sort + uint4 gather SpMM + log_softmax ----------
__global__ __launch_bounds__(512) void LINK_62689342652831_spmm_kernel(
    const unsigned int* __restrict__ packed, const int* __restrict__ bstart,
    const unsigned short* __restrict__ Wtb, const float* __restrict__ bias,
    float* __restrict__ out) {
    __shared__ unsigned int sh[8192];        // sorted (<=6144) OR acc (fallback, 32 KB)
    __shared__ int rhist[BROWS];
    __shared__ int rstart[BROWS + 1];
    __shared__ int rcur[BROWS];
    unsigned int* sorted = sh;

    int lane = threadIdx.x & 63;
    int wid = threadIdx.x >> 6;  // 0..7
    int b = blockIdx.x;
    int s = bstart[b], e = bstart[b + 1];
    int n = e - s;

    if (n <= STAGECAP) {
        // phase A: load edges to registers once + histogram
        unsigned int pk[12];
        if (threadIdx.x < BROWS) rhist[threadIdx.x] = 0;
        __syncthreads();
#pragma unroll
        for (int k = 0; k < 12; ++k) {
            int idx = threadIdx.x + k * 512;
            pk[k] = 0u;
            if (idx < n) {
                pk[k] = packed[s + idx];
                atomicAdd(&rhist[pk[k] >> 17], 1);
            }
        }
        __syncthreads();
        // phase B: 128-entry exclusive scan (one wave)
        if (wid == 0) {
            int c0 = rhist[lane], c1 = rhist[lane + 64];
            int x0 = c0, x1 = c1;
            for (int off = 1; off < 64; off <<= 1) {
                int y0 = __shfl_up(x0, off, 64);
                int y1 = __shfl_up(x1, off, 64);
                if (lane >= off) { x0 += y0; x1 += y1; }
            }
            int t0 = __shfl(x0, 63, 64);
            rstart[lane] = x0 - c0;
            rstart[lane + 64] = x1 - c1 + t0;
            rcur[lane] = x0 - c0;
            rcur[lane + 64] = x1 - c1 + t0;
            if (lane == 63) rstart[128] = x1 + t0;
        }
        __syncthreads();
        // phase C: scatter from registers into row-sorted LDS
#pragma unroll
        for (int k = 0; k < 12; ++k) {
            int idx = threadIdx.x + k * 512;
            if (idx < n) {
                int pos = atomicAdd(&rcur[pk[k] >> 17], 1);
                sorted[pos] = pk[k];
            }
        }
        __syncthreads();

        // phase D: gather — 8 lanes/edge (uint4 = 8 bf16 ch/lane), 8 edges/wave
        const uint4* Wt4 = (const uint4*)Wtb;  // row stride = 8 uint4 (128 B)
        int g = lane >> 3;   // edge slot 0..7
        int gl = lane & 7;   // channel block: 8*gl .. 8*gl+7
        float4 bA = *(const float4*)&bias[8 * gl];
        float4 bB = *(const float4*)&bias[8 * gl + 4];

        for (int r = wid; r < BROWS; r += 8) {
            int gr = b * BROWS + r;
            if (gr >= NUM_NODES) continue;
            int s0 = rstart[r], e0 = rstart[r + 1];
            float a0 = 0, a1 = 0, a2 = 0, a3 = 0, a4 = 0, a5 = 0, a6 = 0, a7 = 0;
            int i = s0 + g;
            for (; i + 8 < e0; i += 16) {  // 2 edges per slot in flight
                unsigned int ua = sorted[i], ub = sorted[i + 8];
                uint4 wa = Wt4[(ua & 0x1FFFF) * 8 + gl];
                uint4 wb = Wt4[(ub & 0x1FFFF) * 8 + gl];
                a0 += __uint_as_float(wa.x << 16);
                a1 += __uint_as_float(wa.x & 0xFFFF0000u);
                a2 += __uint_as_float(wa.y << 16);
                a3 += __uint_as_float(wa.y & 0xFFFF0000u);
                a4 += __uint_as_float(wa.z << 16);
                a5 += __uint_as_float(wa.z & 0xFFFF0000u);
                a6 += __uint_as_float(wa.w << 16);
                a7 += __uint_as_float(wa.w & 0xFFFF0000u);
                a0 += __uint_as_float(wb.x << 16);
                a1 += __uint_as_float(wb.x & 0xFFFF0000u);
                a2 += __uint_as_float(wb.y << 16);
                a3 += __uint_as_float(wb.y & 0xFFFF0000u);
                a4 += __uint_as_float(wb.z << 16);
                a5 += __uint_as_float(wb.z & 0xFFFF0000u);
                a6 += __uint_as_float(wb.w << 16);
                a7 += __uint_as_float(wb.w & 0xFFFF0000u);
            }
            for (; i < e0; i += 8) {
                unsigned int u = sorted[i];
                uint4 w = Wt4[(u & 0x1FFFF) * 8 + gl];
                a0 += __uint_as_float(w.x << 16);
                a1 += __uint_as_float(w.x & 0xFFFF0000u);
                a2 += __uint_as_float(w.y << 16);
                a3 += __uint_as_float(w.y & 0xFFFF0000u);
                a4 += __uint_as_float(w.z << 16);
                a5 += __uint_as_float(w.z & 0xFFFF0000u);
                a6 += __uint_as_float(w.w << 16);
                a7 += __uint_as_float(w.w & 0xFFFF0000u);
            }
            // reduce across the 8 edge slots (lane bits 3..5)
#pragma unroll
            for (int off = 8; off <= 32; off <<= 1) {
                a0 += __shfl_xor(a0, off, 64); a1 += __shfl_xor(a1, off, 64);
                a2 += __shfl_xor(a2, off, 64); a3 += __shfl_xor(a3, off, 64);
                a4 += __shfl_xor(a4, off, 64); a5 += __shfl_xor(a5, off, 64);
                a6 += __shfl_xor(a6, off, 64); a7 += __shfl_xor(a7, off, 64);
            }
            float x0 = a0 + bA.x, x1 = a1 + bA.y, x2 = a2 + bA.z, x3 = a3 + bA.w;
            float x4 = a4 + bB.x, x5 = a5 + bB.y, x6 = a6 + bB.z, x7 = a7 + bB.w;
            float m = fmaxf(fmaxf(fmaxf(x0, x1), fmaxf(x2, x3)),
                            fmaxf(fmaxf(x4, x5), fmaxf(x6, x7)));
            for (int off = 1; off <= 4; off <<= 1) m = fmaxf(m, __shfl_xor(m, off, 64));
            float ssum = expf(x0 - m) + expf(x1 - m) + expf(x2 - m) + expf(x3 - m) +
                         expf(x4 - m) + expf(x5 - m) + expf(x6 - m) + expf(x7 - m);
            for (int off = 1; off <= 4; off <<= 1) ssum += __shfl_xor(ssum, off, 64);
            float l = m + logf(ssum);
            if (g == 0) {
                float4 oA = {x0 - l, x1 - l, x2 - l, x3 - l};
                float4 oB = {x4 - l, x5 - l, x6 - l, x7 - l};
                *(float4*)&out[(size_t)gr * OUT_CH + 8 * gl] = oA;
                *(float4*)&out[(size_t)gr * OUT_CH + 8 * gl + 4] = oB;
            }
        }
    } else {
        // overflow fallback: LDS-atomic accumulate (correct, ~never taken)
        float* acc = (float*)sh;  // 8192 floats = 32 KB
        for (int i = threadIdx.x; i < BROWS * OUT_CH; i += 512) acc[i] = 0.0f;
        __syncthreads();
        for (int i = s + wid; i < e; i += 8) {
            unsigned int u = packed[i];
            float v = __uint_as_float((unsigned int)Wtb[(size_t)(u & 0x1FFFF) * OUT_CH + lane] << 16);
            atomicAdd(&acc[(u >> 17) * OUT_CH + lane], v);
        }
        __syncthreads();
        float bsv = bias[lane];
        for (int r = wid; r < BROWS; r += 8) {
            int gr = b * BROWS + r;
            if (gr >= NUM_NODES) continue;
            float x = acc[r * OUT_CH + lane] + bsv;
            float m = x;
            for (int off = 32; off > 0; off >>= 1) m = fmaxf(m, __shfl_xor(m, off, 64));
            float ex = expf(x - m);
            float ssum = ex;
            for (int off = 32; off > 0; off >>= 1) ssum += __shfl_xor(ssum, off, 64);
            out[(size_t)gr * OUT_CH + lane] = x - m - logf(ssum);
        }
    }
}

// ---------- fallback (round-1 path, direct W) ----------
__global__ void LINK_62689342652831_minf_kernel(const int* __restrict__ rows, int n,
                                                int* __restrict__ minp) {
    int tid = blockIdx.x * blockDim.x + threadIdx.x;
    int stride = gridDim.x * blockDim.x;
    int m = INT_MAX;
    for (int i = tid; i < n; i += stride) m = min(m, rows[i]);
    for (int off = 32; off > 0; off >>= 1) m = min(m, __shfl_xor(m, off, 64));
    if ((threadIdx.x & 63) == 0) atomicMin(minp, m);
}

__global__ void LINK_62689342652831_scatter_kernel(const int* __restrict__ rows,
                                                   const int* __restrict__ cols,
                                                   const float* __restrict__ W,
                                                   const int* __restrict__ minp,
                                                   float* __restrict__ out) {
    int lane = threadIdx.x & 63;
    int gw = (blockIdx.x * blockDim.x + threadIdx.x) >> 6;
    int nw = (gridDim.x * blockDim.x) >> 6;
    int minv = *minp;
    for (int e = gw; e < NUM_EDGES; e += nw) {
        int r = rows[e] - minv;
        int c = cols[e];
        float v = W[(size_t)lane * NUM_NODES + c];
        unsafeAtomicAdd(&out[(size_t)r * 64 + lane], v);
    }
}

__global__ void LINK_62689342652831_logsoftmax_kernel(float* __restrict__ out,
                                                      const float* __restrict__ bias) {
    int lane = threadIdx.x & 63;
    int gw = (blockIdx.x * blockDim.x + threadIdx.x) >> 6;
    int nw = (gridDim.x * blockDim.x) >> 6;
    float b = bias[lane];
    for (int r = gw; r < NUM_NODES; r += nw) {
        float x = out[(size_t)r * 64 + lane] + b;
        float m = x;
        for (int off = 32; off > 0; off >>= 1) m = fmaxf(m, __shfl_xor(m, off, 64));
        float e = expf(x - m);
        float s = e;
        for (int off = 32; off > 0; off >>= 1) s += __shfl_xor(s, off, 64);
        out[(size_t)r * 64 + lane] = x - m - logf(s);
    }
}

extern "C" void kernel_launch(void* const* d_in, const int* in_sizes, int n_in,
                              void* d_out, int out_size, void* d_ws, size_t ws_size,
                              hipStream_t stream) {
    const int* edges = (const int*)d_in[0];
    const int* rows = edges;
    const int* cols = edges + NUM_EDGES;
    const float* W = (const float*)d_in[1];
    const float* bias = (const float*)d_in[2];
    float* out = (float*)d_out;

    // workspace layout
    char* ws = (char*)d_ws;
    const size_t OFF_MIN = 0;                                  // 4 B
    const size_t OFF_BSTART = 256;                             // (NBUCK+1)*4 = 3132 B
    const size_t OFF_TOT = 4096;                               // NBUCK*4 B
    const size_t OFF_H2D = 8192;                               // 256*782*4 = 800768 B
    const size_t OFF_PACKED = 1024 * 1024;                     // 12.8 MB
    const size_t OFF_WTB = OFF_PACKED + (size_t)NUM_EDGES * 4; // 12.8 MB
    const size_t need = OFF_WTB + (size_t)NUM_NODES * OUT_CH * 2;

    int* minp = (int*)(ws + OFF_MIN);
    int* bstart = (int*)(ws + OFF_BSTART);
    int* totals = (int*)(ws + OFF_TOT);
    int* hist2d = (int*)(ws + OFF_H2D);
    unsigned int* packed = (unsigned int*)(ws + OFF_PACKED);
    unsigned short* Wtb = (unsigned short*)(ws + OFF_WTB);

    hipMemsetAsync(minp, 0x7f, sizeof(int), stream);

    if (ws_size >= need) {
        LINK_62689342652831_mintrans_kernel<<<NTRANS + 256, 256, 0, stream>>>(W, Wtb, rows, minp);
        LINK_62689342652831_hist2d_kernel<<<NPBLK, 512, 0, stream>>>(rows, minp, hist2d);
        LINK_62689342652831_colscan_kernel<<<(NBUCK + 7) / 8, 512, 0, stream>>>(hist2d, totals);
        LINK_62689342652831_bscan_kernel<<<1, 1024, 0, stream>>>(totals, bstart);
        LINK_62689342652831_part_kernel<<<NPBLK, 512, 0, stream>>>(rows, cols, minp, hist2d,
                                                                   bstart, packed);
        LINK_62689342652831_spmm_kernel<<<NBUCK, 512, 0, stream>>>(packed, bstart, Wtb,
                                                                   bias, out);
    } else {
        LINK_62689342652831_minf_kernel<<<2048, 256, 0, stream>>>(rows, NUM_EDGES, minp);
        hipMemsetAsync(d_out, 0, (size_t)out_size * sizeof(float), stream);
        LINK_62689342652831_scatter_kernel<<<2048, 256, 0, stream>>>(rows, cols, W, minp, out);
        LINK_62689342652831_logsoftmax_kernel<<<4096, 256, 0, stream>>>(out, bias);
    }
}

// Round 10
// 136.914 us; speedup vs baseline: 1.0086x; 1.0086x over previous
//
#include <hip/hip_runtime.h>
#include <hip/hip_bf16.h>
#include <limits.h>

#define NUM_NODES 100000
#define OUT_CH 64
#define NUM_EDGES 3200000
#define BROWS 64                     // rows per bucket
#define BSHIFT 6
#define NBUCK 1563                   // ceil(100000/64); 1563*64 = 100032
#define NPBLK 256                    // partition blocks
#define EPB (NUM_EDGES / NPBLK)      // 12500 edges per partition block
#define I4PB (EPB / 4)               // 3125 int4 per partition block
#define STAGECAP 4096                // per-bucket LDS sort cap (avg 2046, sigma~45)
#define NTRANS 1563                  // transpose blocks: ceil(100000/64)

// ---------- K1: fused [transpose W -> bf16 Wtb] + [two-stage min] ----------
__global__ __launch_bounds__(256) void LINK_62689342652831_mintrans_kernel(
    const float* __restrict__ W, unsigned short* __restrict__ Wtb,
    const int* __restrict__ rows, int* __restrict__ minp) {
    __shared__ float tile[64][65];
    if (blockIdx.x < NTRANS) {
        int n0 = blockIdx.x * 64;
        int tx = threadIdx.x & 63;
        int ty = threadIdx.x >> 6;
        for (int c = ty; c < 64; c += 4) {
            int n = n0 + tx;
            tile[c][tx] = (n < NUM_NODES) ? W[(size_t)c * NUM_NODES + n] : 0.0f;
        }
        __syncthreads();
        for (int i = ty; i < 64; i += 4) {
            int n = n0 + i;
            if (n < NUM_NODES) {
                __hip_bfloat16 bv = __float2bfloat16(tile[tx][i]);
                Wtb[(size_t)n * OUT_CH + tx] = *(unsigned short*)&bv;
            }
        }
    } else {
        int blk = blockIdx.x - NTRANS;  // 0..255
        int tid = blk * 256 + threadIdx.x;
        int stride = 256 * 256;
        const int4* r4 = (const int4*)rows;
        int m = INT_MAX;
        for (int i = tid; i < NUM_EDGES / 4; i += stride) {
            int4 v = r4[i];
            m = min(m, min(min(v.x, v.y), min(v.z, v.w)));
        }
        for (int off = 32; off > 0; off >>= 1) m = min(m, __shfl_xor(m, off, 64));
        int* sm = (int*)tile;
        if ((threadIdx.x & 63) == 0) sm[threadIdx.x >> 6] = m;
        __syncthreads();
        if (threadIdx.x == 0) {
            int mm = min(min(sm[0], sm[1]), min(sm[2], sm[3]));
            atomicMin(minp, mm);
        }
    }
}

// ---------- K3: per-block bucket histogram -> hist2d[blk][bucket] ----------
__global__ __launch_bounds__(512) void LINK_62689342652831_hist2d_kernel(
    const int* __restrict__ rows, const int* __restrict__ minp,
    int* __restrict__ hist2d) {
    __shared__ int h[NBUCK];
    for (int i = threadIdx.x; i < NBUCK; i += 512) h[i] = 0;
    __syncthreads();
    int minv = *minp;
    int blk = blockIdx.x;
    const int4* r4 = (const int4*)rows;
    for (int i = threadIdx.x; i < I4PB; i += 512) {
        int4 v = r4[blk * I4PB + i];
        atomicAdd(&h[(unsigned)(v.x - minv) >> BSHIFT], 1);
        atomicAdd(&h[(unsigned)(v.y - minv) >> BSHIFT], 1);
        atomicAdd(&h[(unsigned)(v.z - minv) >> BSHIFT], 1);
        atomicAdd(&h[(unsigned)(v.w - minv) >> BSHIFT], 1);
    }
    __syncthreads();
    for (int i = threadIdx.x; i < NBUCK; i += 512) hist2d[blk * NBUCK + i] = h[i];
}

// ---------- K4a: per-bucket prefix over the 256 blocks (in-place) ----------
__global__ __launch_bounds__(512) void LINK_62689342652831_colscan_kernel(
    int* __restrict__ hist2d, int* __restrict__ totals) {
    int lane = threadIdx.x & 63;
    int wid = threadIdx.x >> 6;
    int b = blockIdx.x * 8 + wid;
    if (b >= NBUCK) return;
    int carry = 0;
    for (int rnd = 0; rnd < NPBLK / 64; ++rnd) {
        int blk = rnd * 64 + lane;
        int v = hist2d[blk * NBUCK + b];
        int x = v;
        for (int off = 1; off < 64; off <<= 1) {
            int y = __shfl_up(x, off, 64);
            if (lane >= off) x += y;
        }
        hist2d[blk * NBUCK + b] = x - v + carry;  // exclusive + carry
        carry += __shfl(x, 63, 64);
    }
    if (lane == 0) totals[b] = carry;
}

// ---------- K4b: scan bucket totals (2/thread) -> bstart[0..NBUCK] ----------
__global__ __launch_bounds__(1024) void LINK_62689342652831_bscan_kernel(
    const int* __restrict__ totals, int* __restrict__ bstart) {
    __shared__ int ss[1024];
    int t = threadIdx.x;
    int i0 = 2 * t, i1 = 2 * t + 1;
    int v0 = (i0 < NBUCK) ? totals[i0] : 0;
    int v1 = (i1 < NBUCK) ? totals[i1] : 0;
    int p1 = v0 + v1;
    ss[t] = p1;
    __syncthreads();
    for (int off = 1; off < 1024; off <<= 1) {
        int x = (t >= off) ? ss[t - off] : 0;
        __syncthreads();
        ss[t] += x;
        __syncthreads();
    }
    int texcl = ss[t] - p1;
    if (i0 < NBUCK) bstart[i0] = texcl;
    if (i1 < NBUCK) bstart[i1] = texcl + v0;
    if (t == 1023) bstart[NBUCK] = ss[1023];
}

// ---------- K5: partition edges into bucket regions (no global atomics) ----------
__global__ __launch_bounds__(512) void LINK_62689342652831_part_kernel(
    const int* __restrict__ rows, const int* __restrict__ cols,
    const int* __restrict__ minp, const int* __restrict__ hist2d,
    const int* __restrict__ bstart, unsigned int* __restrict__ packed) {
    __shared__ int offs_l[NBUCK];
    __shared__ int lcur[NBUCK];
    int blk = blockIdx.x;
    for (int i = threadIdx.x; i < NBUCK; i += 512) {
        offs_l[i] = bstart[i] + hist2d[blk * NBUCK + i];
        lcur[i] = 0;
    }
    __syncthreads();
    int minv = *minp;
    const int4* r4 = (const int4*)rows;
    const int4* c4 = (const int4*)cols;
    for (int i = threadIdx.x; i < I4PB; i += 512) {
        int4 rv = r4[blk * I4PB + i];
        int4 cv = c4[blk * I4PB + i];
#pragma unroll
        for (int k = 0; k < 4; ++k) {
            int r = ((k == 0) ? rv.x : (k == 1) ? rv.y : (k == 2) ? rv.z : rv.w) - minv;
            int c = (k == 0) ? cv.x : (k == 1) ? cv.y : (k == 2) ? cv.z : cv.w;
            int b = (unsigned)r >> BSHIFT;
            int pos = offs_l[b] + atomicAdd(&lcur[b], 1);
            packed[pos] = ((unsigned)(r & (BROWS - 1)) << 17) | (unsigned)c;
        }
    }
}

// ---------- K6: per-bucket counting-sort + uint2 gather SpMM + log_softmax ----------
__global__ __launch_bounds__(256) void LINK_62689342652831_spmm_kernel(
    const unsigned int* __restrict__ packed, const int* __restrict__ bstart,
    const unsigned short* __restrict__ Wtb, const float* __restrict__ bias,
    float* __restrict__ out) {
    __shared__ unsigned int sorted[STAGECAP];   // 16 KB (fallback reuses as acc)
    __shared__ int rhist[BROWS];
    __shared__ int rstart[BROWS + 1];
    __shared__ int rcur[BROWS];

    int lane = threadIdx.x & 63;
    int wid = threadIdx.x >> 6;  // 0..3
    int b = blockIdx.x;
    int s = bstart[b], e = bstart[b + 1];
    int n = e - s;

    if (n <= STAGECAP) {
        if (threadIdx.x < BROWS) rhist[threadIdx.x] = 0;
        __syncthreads();
        for (int i = threadIdx.x; i < n; i += 256)
            atomicAdd(&rhist[packed[s + i] >> 17], 1);
        __syncthreads();
        if (threadIdx.x < 64) {
            int c0 = rhist[lane];
            int x0 = c0;
            for (int off = 1; off < 64; off <<= 1) {
                int y0 = __shfl_up(x0, off, 64);
                if (lane >= off) x0 += y0;
            }
            rstart[lane] = x0 - c0;
            rcur[lane] = x0 - c0;
            if (lane == 63) rstart[64] = x0;
        }
        __syncthreads();
        for (int i = threadIdx.x; i < n; i += 256) {
            unsigned int u = packed[s + i];
            int pos = atomicAdd(&rcur[u >> 17], 1);
            sorted[pos] = u;
        }
        __syncthreads();

        // gather: 16 lanes/edge (uint2 = 4 bf16 channels/lane), 4 edges/wave
        const uint2* Wt2 = (const uint2*)Wtb;  // row stride = 16 uint2
        int q = lane >> 4;    // quarter 0..3
        int ql = lane & 15;   // channels 4ql .. 4ql+3
        float b0 = bias[4 * ql], b1 = bias[4 * ql + 1],
              b2 = bias[4 * ql + 2], b3 = bias[4 * ql + 3];

        for (int r = wid; r < BROWS; r += 4) {
            int gr = b * BROWS + r;
            if (gr >= NUM_NODES) continue;
            int s0 = rstart[r], e0 = rstart[r + 1];
            float a0 = 0, a1 = 0, a2 = 0, a3 = 0;
            int i = s0 + q;
            for (; i + 4 < e0; i += 8) {  // 2 independent edges in flight
                unsigned int ua = sorted[i], ub = sorted[i + 4];
                uint2 wa = Wt2[(size_t)(ua & 0x1FFFF) * 16 + ql];
                uint2 wb = Wt2[(size_t)(ub & 0x1FFFF) * 16 + ql];
                a0 += __uint_as_float(wa.x << 16);
                a1 += __uint_as_float(wa.x & 0xFFFF0000u);
                a2 += __uint_as_float(wa.y << 16);
                a3 += __uint_as_float(wa.y & 0xFFFF0000u);
                a0 += __uint_as_float(wb.x << 16);
                a1 += __uint_as_float(wb.x & 0xFFFF0000u);
                a2 += __uint_as_float(wb.y << 16);
                a3 += __uint_as_float(wb.y & 0xFFFF0000u);
            }
            for (; i < e0; i += 4) {
                unsigned int u = sorted[i];
                uint2 w = Wt2[(size_t)(u & 0x1FFFF) * 16 + ql];
                a0 += __uint_as_float(w.x << 16);
                a1 += __uint_as_float(w.x & 0xFFFF0000u);
                a2 += __uint_as_float(w.y << 16);
                a3 += __uint_as_float(w.y & 0xFFFF0000u);
            }
            // combine the 4 quarters: lanes with equal ql share channels
            a0 += __shfl_xor(a0, 32, 64); a1 += __shfl_xor(a1, 32, 64);
            a2 += __shfl_xor(a2, 32, 64); a3 += __shfl_xor(a3, 32, 64);
            a0 += __shfl_xor(a0, 16, 64); a1 += __shfl_xor(a1, 16, 64);
            a2 += __shfl_xor(a2, 16, 64); a3 += __shfl_xor(a3, 16, 64);

            float x0 = a0 + b0, x1 = a1 + b1, x2 = a2 + b2, x3 = a3 + b3;
            float m = fmaxf(fmaxf(x0, x1), fmaxf(x2, x3));
            for (int off = 8; off > 0; off >>= 1) m = fmaxf(m, __shfl_xor(m, off, 64));
            float ssum = expf(x0 - m) + expf(x1 - m) + expf(x2 - m) + expf(x3 - m);
            for (int off = 8; off > 0; off >>= 1) ssum += __shfl_xor(ssum, off, 64);
            float l = m + logf(ssum);
            if (lane < 16) {
                float4 o = {x0 - l, x1 - l, x2 - l, x3 - l};
                *(float4*)&out[(size_t)gr * OUT_CH + 4 * ql] = o;
            }
        }
    } else {
        // overflow fallback: LDS-atomic accumulate (correct, ~never taken)
        float* acc = (float*)sorted;  // 64*64 floats = 16 KB
        for (int i = threadIdx.x; i < BROWS * OUT_CH; i += 256) acc[i] = 0.0f;
        __syncthreads();
        for (int i = s + wid; i < e; i += 4) {
            unsigned int u = packed[i];
            float v = __uint_as_float((unsigned int)Wtb[(size_t)(u & 0x1FFFF) * OUT_CH + lane] << 16);
            atomicAdd(&acc[(u >> 17) * OUT_CH + lane], v);
        }
        __syncthreads();
        float bsv = bias[lane];
        for (int r = wid; r < BROWS; r += 4) {
            int gr = b * BROWS + r;
            if (gr >= NUM_NODES) continue;
            float x = acc[r * OUT_CH + lane] + bsv;
            float m = x;
            for (int off = 32; off > 0; off >>= 1) m = fmaxf(m, __shfl_xor(m, off, 64));
            float ex = expf(x - m);
            float ssum = ex;
            for (int off = 32; off > 0; off >>= 1) ssum += __shfl_xor(ssum, off, 64);
            out[(size_t)gr * OUT_CH + lane] = x - m - logf(ssum);
        }
    }
}

// ---------- fallback (round-1 path, direct W) ----------
__global__ void LINK_62689342652831_minf_kernel(const int* __restrict__ rows, int n,
                                                int* __restrict__ minp) {
    int tid = blockIdx.x * blockDim.x + threadIdx.x;
    int stride = gridDim.x * blockDim.x;
    int m = INT_MAX;
    for (int i = tid; i < n; i += stride) m = min(m, rows[i]);
    for (int off = 32; off > 0; off >>= 1) m = min(m, __shfl_xor(m, off, 64));
    if ((threadIdx.x & 63) == 0) atomicMin(minp, m);
}

__global__ void LINK_62689342652831_scatter_kernel(const int* __restrict__ rows,
                                                   const int* __restrict__ cols,
                                                   const float* __restrict__ W,
                                                   const int* __restrict__ minp,
                                                   float* __restrict__ out) {
    int lane = threadIdx.x & 63;
    int gw = (blockIdx.x * blockDim.x + threadIdx.x) >> 6;
    int nw = (gridDim.x * blockDim.x) >> 6;
    int minv = *minp;
    for (int e = gw; e < NUM_EDGES; e += nw) {
        int r = rows[e] - minv;
        int c = cols[e];
        float v = W[(size_t)lane * NUM_NODES + c];
        unsafeAtomicAdd(&out[(size_t)r * 64 + lane], v);
    }
}

__global__ void LINK_62689342652831_logsoftmax_kernel(float* __restrict__ out,
                                                      const float* __restrict__ bias) {
    int lane = threadIdx.x & 63;
    int gw = (blockIdx.x * blockDim.x + threadIdx.x) >> 6;
    int nw = (gridDim.x * blockDim.x) >> 6;
    float b = bias[lane];
    for (int r = gw; r < NUM_NODES; r += nw) {
        float x = out[(size_t)r * 64 + lane] + b;
        float m = x;
        for (int off = 32; off > 0; off >>= 1) m = fmaxf(m, __shfl_xor(m, off, 64));
        float e = expf(x - m);
        float s = e;
        for (int off = 32; off > 0; off >>= 1) s += __shfl_xor(s, off, 64);
        out[(size_t)r * 64 + lane] = x - m - logf(s);
    }
}

extern "C" void kernel_launch(void* const* d_in, const int* in_sizes, int n_in,
                              void* d_out, int out_size, void* d_ws, size_t ws_size,
                              hipStream_t stream) {
    const int* edges = (const int*)d_in[0];
    const int* rows = edges;
    const int* cols = edges + NUM_EDGES;
    const float* W = (const float*)d_in[1];
    const float* bias = (const float*)d_in[2];
    float* out = (float*)d_out;

    // workspace layout
    char* ws = (char*)d_ws;
    const size_t OFF_MIN = 0;                                  // 4 B
    const size_t OFF_BSTART = 256;                             // (NBUCK+1)*4 = 6256 B
    const size_t OFF_TOT = 8192;                               // NBUCK*4 = 6252 B
    const size_t OFF_H2D = 16384;                              // 256*1563*4 = 1600512 B
    const size_t OFF_PACKED = 2 * 1024 * 1024;                 // 12.8 MB
    const size_t OFF_WTB = OFF_PACKED + (size_t)NUM_EDGES * 4; // 12.8 MB
    const size_t need = OFF_WTB + (size_t)NUM_NODES * OUT_CH * 2;

    int* minp = (int*)(ws + OFF_MIN);
    int* bstart = (int*)(ws + OFF_BSTART);
    int* totals = (int*)(ws + OFF_TOT);
    int* hist2d = (int*)(ws + OFF_H2D);
    unsigned int* packed = (unsigned int*)(ws + OFF_PACKED);
    unsigned short* Wtb = (unsigned short*)(ws + OFF_WTB);

    hipMemsetAsync(minp, 0x7f, sizeof(int), stream);

    if (ws_size >= need) {
        LINK_62689342652831_mintrans_kernel<<<NTRANS + 256, 256, 0, stream>>>(W, Wtb, rows, minp);
        LINK_62689342652831_hist2d_kernel<<<NPBLK, 512, 0, stream>>>(rows, minp, hist2d);
        LINK_62689342652831_colscan_kernel<<<(NBUCK + 7) / 8, 512, 0, stream>>>(hist2d, totals);
        LINK_62689342652831_bscan_kernel<<<1, 1024, 0, stream>>>(totals, bstart);
        LINK_62689342652831_part_kernel<<<NPBLK, 512, 0, stream>>>(rows, cols, minp, hist2d,
                                                                   bstart, packed);
        LINK_62689342652831_spmm_kernel<<<NBUCK, 256, 0, stream>>>(packed, bstart, Wtb,
                                                                   bias, out);
    } else {
        LINK_62689342652831_minf_kernel<<<2048, 256, 0, stream>>>(rows, NUM_EDGES, minp);
        hipMemsetAsync(d_out, 0, (size_t)out_size * sizeof(float), stream);
        LINK_62689342652831_scatter_kernel<<<2048, 256, 0, stream>>>(rows, cols, W, minp, out);
        LINK_62689342652831_logsoftmax_kernel<<<4096, 256, 0, stream>>>(out, bias);
    }
}